// Round 1
// baseline (418.760 us; speedup 1.0000x reference)
//
#include <hip/hip_runtime.h>
#include <hip/hip_bf16.h>
#include <math.h>

#define B_ 8
#define W_ 1024
#define D_ 1024
#define R_ 64

typedef __hip_bfloat16 bf16;
typedef __attribute__((ext_vector_type(8))) short bf16x8;   // MFMA A/B frag (4 VGPRs)
typedef __attribute__((ext_vector_type(4))) float f32x4;    // MFMA C/D frag

__device__ __forceinline__ float tof(bf16 x) { return __bfloat162float(x); }
__device__ __forceinline__ short f2bs(float f) {
    bf16 b = __float2bfloat16(f);
    return *(short*)&b;
}

// async global->LDS, 16 bytes/lane; LDS dest = wave-uniform base + lane*16
__device__ __forceinline__ void async16(const void* g, void* l) {
    __builtin_amdgcn_global_load_lds(
        (const __attribute__((address_space(1))) unsigned int*)g,
        (__attribute__((address_space(3))) unsigned int*)l,
        16, 0, 0);
}

// ---------------------------------------------------------------------------
// RMSNorm: one block (256 threads) per row of D_=1024. fp32 in, bf16 out.
// ---------------------------------------------------------------------------
__global__ __launch_bounds__(256)
void rmsnorm_kernel(const float* __restrict__ src, const float* __restrict__ scale,
                    bf16* __restrict__ dst) {
    int row = blockIdx.x;
    const float* x = src + (size_t)row * D_;
    bf16* y = dst + (size_t)row * D_;
    float xv[4];
    float ss = 0.f;
#pragma unroll
    for (int it = 0; it < 4; ++it) {
        int d = threadIdx.x + it * 256;
        xv[it] = x[d];
        ss += xv[it] * xv[it];
    }
#pragma unroll
    for (int off = 32; off; off >>= 1) ss += __shfl_down(ss, off, 64);
    __shared__ float red[4];
    __shared__ float invs;
    int lane = threadIdx.x & 63, wid = threadIdx.x >> 6;
    if (lane == 0) red[wid] = ss;
    __syncthreads();
    if (threadIdx.x == 0) {
        float t = red[0] + red[1] + red[2] + red[3];
        invs = rsqrtf(t / (float)D_ + 1e-8f);
    }
    __syncthreads();
    float inv = invs;
#pragma unroll
    for (int it = 0; it < 4; ++it) {
        int d = threadIdx.x + it * 256;
        y[d] = __float2bfloat16(xv[it] * inv * scale[d]);
    }
}

// ---------------------------------------------------------------------------
// 64x64 LDS-tiled transpose: src[b][j][d] -> dst[b][d][j]  (bf16)
// ---------------------------------------------------------------------------
__global__ __launch_bounds__(256)
void transpose_kernel(const bf16* __restrict__ src, bf16* __restrict__ dst) {
    int b = blockIdx.z;
    int j0 = blockIdx.x * 64, d0 = blockIdx.y * 64;
    __shared__ short Ts[64][72];
    const bf16* S = src + (size_t)b * W_ * D_;
    bf16* Dd = dst + (size_t)b * W_ * D_;
    int tid = threadIdx.x;
    int r = tid >> 3, c = (tid & 7) * 8;
#pragma unroll
    for (int p = 0; p < 2; ++p) {
        int j = r + p * 32;
        bf16x8 vv = *(const bf16x8*)&S[(size_t)(j0 + j) * D_ + d0 + c];
#pragma unroll
        for (int e = 0; e < 8; ++e) Ts[j][c + e] = vv[e];
    }
    __syncthreads();
#pragma unroll
    for (int p = 0; p < 2; ++p) {
        int d = r + p * 32;
        bf16x8 vv;
#pragma unroll
        for (int e = 0; e < 8; ++e) vv[e] = Ts[c + e][d];
        *(bf16x8*)&Dd[(size_t)(d0 + d) * W_ + j0 + c] = vv;
    }
}

// ---------------------------------------------------------------------------
// uvT[r][d] (bf16, [128][1024]) from u[d][64] (z=0) and v[d][64] (z=1).
// ---------------------------------------------------------------------------
__global__ __launch_bounds__(256)
void uvT_kernel(const float* __restrict__ u, const float* __restrict__ v,
                bf16* __restrict__ uvT) {
    int g = blockIdx.z;
    int d0 = blockIdx.x * 64;
    const float* src = g ? v : u;
    __shared__ float Ts[64][65];
    int tid = threadIdx.x;
#pragma unroll
    for (int e = 0; e < 16; ++e) {
        int idx = tid + e * 256;
        int drow = idx >> 6, rcol = idx & 63;
        Ts[drow][rcol] = src[(size_t)(d0 + drow) * 64 + rcol];
    }
    __syncthreads();
#pragma unroll
    for (int e = 0; e < 16; ++e) {
        int idx = tid + e * 256;
        int orow = idx >> 6, ocol = idx & 63;
        uvT[(size_t)(g * 64 + orow) * D_ + d0 + ocol] = __float2bfloat16(Ts[ocol][orow]);
    }
}

// ---------------------------------------------------------------------------
// fp32 -> bf16 convert of the three weight matrices in ONE launch.
// ---------------------------------------------------------------------------
__global__ __launch_bounds__(256)
void convert3_kernel(const float* __restrict__ proj, const float* __restrict__ up,
                     const float* __restrict__ down,
                     bf16* __restrict__ projb, bf16* __restrict__ upb,
                     bf16* __restrict__ downb) {
    size_t idx = ((size_t)blockIdx.x * 256 + threadIdx.x) * 8;
    const size_t DD = (size_t)D_ * D_;
    const float* src; bf16* dst; size_t off;
    if (idx < DD)          { src = proj; dst = projb; off = idx; }
    else if (idx < 3 * DD) { src = up;   dst = upb;   off = idx - DD; }
    else                   { src = down; dst = downb; off = idx - 3 * DD; }
    float4 f0 = *(const float4*)(src + off);
    float4 f1 = *(const float4*)(src + off + 4);
    bf16x8 p;
    p[0] = f2bs(f0.x); p[1] = f2bs(f0.y); p[2] = f2bs(f0.z); p[3] = f2bs(f0.w);
    p[4] = f2bs(f1.x); p[5] = f2bs(f1.y); p[6] = f2bs(f1.z); p[7] = f2bs(f1.w);
    *(bf16x8*)(dst + off) = p;
}

// ---------------------------------------------------------------------------
// qk epilogue: sum SK=4 fp32 partials, l2norm halves, gamma^{+/-i} -> qg, kg.
// ---------------------------------------------------------------------------
__global__ __launch_bounds__(128)
void qk_epilogue_kernel(const float* __restrict__ qkraw,
                        const float* __restrict__ decay_logit,
                        float* __restrict__ qg, float* __restrict__ kg) {
    int row = blockIdx.x;          // b*W + i
    int i = row & (W_ - 1);
    int t = threadIdx.x;
    int r = t & 63;
    bool isK = t >= 64;
    const size_t PS = (size_t)B_ * W_ * 128;   // partial stride
    size_t off = (size_t)row * 128 + t;
    float val = qkraw[off] + qkraw[PS + off] + qkraw[2 * PS + off] + qkraw[3 * PS + off];
    float sq = val * val;
#pragma unroll
    for (int o = 32; o; o >>= 1) sq += __shfl_xor(sq, o, 64);
    val = val / fmaxf(sqrtf(sq), 1e-8f);

    float dl = decay_logit[r];
    float gamma = 0.15f + 0.85f * (1.f / (1.f + expf(-dl)));
    float lg = logf(gamma);
    float e = isK ? expf(-(float)i * lg) : expf((float)i * lg);
    float o = val * e;
    if (isK) kg[(size_t)row * R_ + r] = o;
    else     qg[(size_t)row * R_ + r] = o;
}

// ---------------------------------------------------------------------------
// M[b,i,j] = (j<=i) ? gate*k_base[i,j] + alpha * dot(qg[b,i,:], kg[b,j,:]) : 0
// ---------------------------------------------------------------------------
__global__ __launch_bounds__(256)
void buildM_kernel(const float* __restrict__ qg, const float* __restrict__ kg,
                   const float* __restrict__ k_base,
                   const float* __restrict__ gate_logit,
                   const float* __restrict__ alpha_logit,
                   bf16* __restrict__ M) {
    int b = blockIdx.z;
    int ti = blockIdx.y, tj = blockIdx.x;
    int i0 = ti * 32, j0 = tj * 32;
    int tx = threadIdx.x, ty = threadIdx.y;
    bf16* Mb = M + (size_t)b * W_ * W_;
    const bf16 zero = __float2bfloat16(0.f);

    if (tj > ti) {
#pragma unroll
        for (int a = 0; a < 2; ++a)
#pragma unroll
            for (int c = 0; c < 2; ++c)
                Mb[(size_t)(i0 + ty * 2 + a) * W_ + (j0 + tx * 2 + c)] = zero;
        return;
    }

    __shared__ float Qs[32][65];
    __shared__ float Ks[32][65];
    int tid = ty * 16 + tx;
    for (int e = tid; e < 32 * 64; e += 256) {
        int rr = e & 63, row = e >> 6;
        Qs[row][rr] = qg[((size_t)b * W_ + i0 + row) * R_ + rr];
        Ks[row][rr] = kg[((size_t)b * W_ + j0 + row) * R_ + rr];
    }
    __syncthreads();

    float acc[2][2] = {{0.f, 0.f}, {0.f, 0.f}};
#pragma unroll 8
    for (int r = 0; r < 64; ++r) {
        float qa = Qs[ty * 2 + 0][r], qb = Qs[ty * 2 + 1][r];
        float ka = Ks[tx * 2 + 0][r], kb = Ks[tx * 2 + 1][r];
        acc[0][0] += qa * ka; acc[0][1] += qa * kb;
        acc[1][0] += qb * ka; acc[1][1] += qb * kb;
    }

    float gate  = 1.f / (1.f + expf(-(*gate_logit)));
    float alpha = 1.f / (1.f + expf(-(*alpha_logit)));  // ALPHA_CAP = 1
#pragma unroll
    for (int a = 0; a < 2; ++a) {
#pragma unroll
        for (int c = 0; c < 2; ++c) {
            int i = i0 + ty * 2 + a, j = j0 + tx * 2 + c;
            float vkb = k_base[(size_t)i * W_ + j];
            float out = (j <= i) ? (gate * vkb + alpha * acc[a][c]) : 0.f;
            Mb[(size_t)i * W_ + j] = __float2bfloat16(out);
        }
    }
}

// ---------------------------------------------------------------------------
// OLD MFMA GEMM (128x128, 2-phase): kept only for step 2 (N=128 split-K).
// EPI 5: Cout fp32 partial at z*sC (deterministic split-K)
// ---------------------------------------------------------------------------
template<int EPI, int SK>
__global__ __launch_bounds__(512)
void mgemm_kernel(const bf16* __restrict__ A, const bf16* __restrict__ Bm,
                  const float* __restrict__ Res, const float* __restrict__ bias,
                  void* __restrict__ Cout,
                  int M, int N, int K,
                  long sA, long sB, long sC, int causal) {
    __shared__ __align__(16) short At[2][128 * 32];
    __shared__ __align__(16) short Bt[2][128 * 32];
    int z = blockIdx.z;
    const bf16* Ab = (SK > 1) ? A : A + (size_t)z * sA;
    const bf16* Bb = (SK > 1) ? Bm : Bm + (size_t)z * sB;
    int kchunk = K / SK;
    int kbeg = (SK > 1) ? z * kchunk : 0;
    int m0 = blockIdx.x * 128, n0 = blockIdx.y * 128;   // transposed grid
    int tid = threadIdx.x;
    int lane = tid & 63, wave = tid >> 6;               // wave 0..7
    int wy = wave >> 1, wx = wave & 1;
    int quad = lane >> 4, l15 = lane & 15;

    f32x4 acc[2][4];
#pragma unroll
    for (int i = 0; i < 2; ++i)
#pragma unroll
        for (int j = 0; j < 4; ++j)
            acc[i][j] = (f32x4){0.f, 0.f, 0.f, 0.f};

    int kend = kbeg + kchunk;
    if (SK == 1 && causal) kend = (m0 + 128 < K) ? m0 + 128 : K;
    int nIter = (kend - kbeg) >> 5;

    int srcChunk = ((lane & 3) ^ ((lane >> 3) & 3)) * 8;
    size_t rowA = (size_t)(m0 + wave * 16 + (lane >> 2)) * K;
    size_t rowB = (size_t)(n0 + wave * 16 + (lane >> 2)) * K;
    const bf16* aP = Ab + rowA + srcChunk + kbeg;
    const bf16* bP = Bb + rowB + srcChunk + kbeg;
    short* dA[2] = { &At[0][wave * 512], &At[1][wave * 512] };
    short* dB[2] = { &Bt[0][wave * 512], &Bt[1][wave * 512] };

    int rswz = (quad ^ ((l15 >> 1) & 3)) * 8;

    async16(aP, dA[0]);
    async16(bP, dB[0]);
    aP += 32; bP += 32;
    __syncthreads();

    for (int it = 0; it < nIter; ++it) {
        int cur = it & 1;
        if (it + 1 < nIter) {
            int nxt = cur ^ 1;
            async16(aP, dA[nxt]);
            async16(bP, dB[nxt]);
            aP += 32; bP += 32;
        }
        bf16x8 af[2], bfr[4];
#pragma unroll
        for (int mi = 0; mi < 2; ++mi)
            af[mi] = *(const bf16x8*)&At[cur][(wy * 32 + mi * 16 + l15) * 32 + rswz];
#pragma unroll
        for (int ni = 0; ni < 4; ++ni)
            bfr[ni] = *(const bf16x8*)&Bt[cur][(wx * 64 + ni * 16 + l15) * 32 + rswz];
#pragma unroll
        for (int mi = 0; mi < 2; ++mi)
#pragma unroll
            for (int ni = 0; ni < 4; ++ni)
                acc[mi][ni] = __builtin_amdgcn_mfma_f32_16x16x32_bf16(
                    af[mi], bfr[ni], acc[mi][ni], 0, 0, 0);
        __syncthreads();
    }

#pragma unroll
    for (int ni = 0; ni < 4; ++ni) {
        int col = n0 + wx * 64 + ni * 16 + l15;
        float bv = (EPI == 1 || EPI == 2) ? bias[col] : 0.f;
#pragma unroll
        for (int mi = 0; mi < 2; ++mi) {
            int row0 = m0 + wy * 32 + mi * 16 + quad * 4;
#pragma unroll
            for (int r = 0; r < 4; ++r) {
                size_t idx = (size_t)(row0 + r) * N + col;
                float val = acc[mi][ni][r];
                if constexpr (EPI == 0) {
                    ((bf16*)Cout)[(size_t)z * sC + idx] = __float2bfloat16(val);
                } else if constexpr (EPI == 1) {
                    ((float*)Cout)[idx] = val + bv + Res[idx];
                } else if constexpr (EPI == 2) {
                    val += bv;
                    val = 0.5f * val * (1.f + erff(val * 0.70710678118654752f));
                    ((bf16*)Cout)[idx] = __float2bfloat16(val);
                } else {
                    ((float*)Cout)[(size_t)z * sC + idx] = val;
                }
            }
        }
    }
}

// ---------------------------------------------------------------------------
// NEW: 256x256 8-phase MFMA GEMM (round-13). C[m,n] = sum_k A[m,k]*B[n,k].
// BM=BN=256, BK=64, 8 waves (2M x 4N), per-wave 128x64 out (acc 8x4 f32x4).
// LDS 128 KiB = dbuf x (A 256x64 + B 256x64) bf16, 1 block/CU.
// Why: old 2-phase kernel = MfmaUtil 17%, HBM 14% -> latency-bound on the
// vmcnt(0) drain at every __syncthreads. This is T3+T4 (8 phases, counted
// vmcnt(6), raw s_barrier pairs) + T5 (setprio around MFMA clusters) +
// chunk-XOR LDS swizzle (conflict-free, same family as old kernel) + T1
// XCD swizzle on M-stripes.
// Pipeline (tile t, buffer p=t&1, half order [Ah0,Ah1,Bh0,Bh1]):
//  ph1: issue Bh1(t+1)->p^1 | read A all(16) + B nh0(4) | bar,lgkm0 | Q(m0,n0) | bar
//  ph2: issue Ah0(t+2)->p   | read B nh1(4)             | bar,lgkm0 | Q(m0,n1) | bar
//  ph3: issue Ah1(t+2)->p   |                           | bar       | Q(m1,n1) | bar
//  ph4: issue Bh0(t+2)->p, vmcnt(6)                     | bar       | Q(m1,n0) | bar
// Safety: A reads complete at ph1's lgkm0 (so Ah writes may issue ph2+);
// B reads complete by ph2 (Bh writes at ph4 / next ph1->other buf). vmcnt(6)
// at ph4 = 3 half-tiles in flight; guarantees tile t+1 fully landed (the 8
// loads issued since Bh1(t+1) leave <=6 outstanding => its 2 landed, rest of
// t+1 issued >=10 back). Epilogue tiles (t+2>=NT) drain with vmcnt(0).
// ---------------------------------------------------------------------------
#define BAR256() do { __builtin_amdgcn_sched_barrier(0); \
                      __builtin_amdgcn_s_barrier(); \
                      __builtin_amdgcn_sched_barrier(0); } while (0)
#define LGKM0() do { asm volatile("s_waitcnt lgkmcnt(0)" ::: "memory"); \
                     __builtin_amdgcn_sched_barrier(0); } while (0)
// IDX: 0=Ah0 1=Ah1 2=Bh0 3=Bh1 ; each = 2 async16/thread (16 KiB total)
#define STAGE(IDX, T) do { \
    const bf16* _g; short* _l; \
    if ((IDX) < 2) { \
        _g = aBase + (size_t)((IDX) * 128) * K + (T) * 64; \
        _l = &At[(T) & 1][(IDX) * 8192 + wave * 1024]; \
    } else { \
        _g = bBase + (size_t)(((IDX) - 2) * 128) * K + (T) * 64; \
        _l = &Bt[(T) & 1][((IDX) - 2) * 8192 + wave * 1024]; \
    } \
    async16(_g, _l); \
    async16(_g + (size_t)8 * K, _l + 512); \
} while (0)
#define RD_A(MI, KS) af[MI][KS] = *(const bf16x8*)&Ard[arow + (MI) * 1024 + ck##KS]
#define RD_B(NI, KS) bfr[NI][KS] = *(const bf16x8*)&Brd[brow + (NI) * 1024 + ck##KS]

template<int EPI>
__global__ __launch_bounds__(512)
void mgemm256_kernel(const bf16* __restrict__ A, const bf16* __restrict__ Bm,
                     const float* __restrict__ Res, const float* __restrict__ bias,
                     void* __restrict__ Cout,
                     int M, int N, int K, long sA, long sB, long sC, int causal) {
    __shared__ __align__(16) short At[2][16384];   // 64 KiB: [256 rows][64 k] bf16
    __shared__ __align__(16) short Bt[2][16384];   // 64 KiB
    int z = blockIdx.z;
    const bf16* Ab = A + (size_t)z * sA;
    const bf16* Bb = Bm + (size_t)z * sB;

    int bx = blockIdx.x, gx = gridDim.x;
    if ((gx & 7) == 0) { int cpx = gx >> 3; bx = (bx & 7) * cpx + (bx >> 3); }  // T1
    int m0 = bx * 256, n0 = blockIdx.y * 256;

    int tid = threadIdx.x;
    int lane = tid & 63, wave = tid >> 6;           // 8 waves
    int wm = wave >> 2, wn = wave & 3;              // 2M x 4N
    int quad = lane >> 4, l15 = lane & 15;

    f32x4 acc[8][4];
#pragma unroll
    for (int i = 0; i < 8; ++i)
#pragma unroll
        for (int j = 0; j < 4; ++j)
            acc[i][j] = (f32x4){0.f, 0.f, 0.f, 0.f};

    int kend = causal ? ((m0 + 256 < K) ? m0 + 256 : K) : K;
    int NT = kend >> 6;                             // >= 4 in all our uses

    // staging: wave w covers rows [w*16, w*16+16) of each 128-row half;
    // lane -> row +(lane>>3), 16B chunk (lane&7), source chunk XOR-swizzled.
    const bf16* aBase = Ab + (size_t)(m0 + wave * 16 + (lane >> 3)) * K
                           + ((lane & 7) ^ (lane >> 3)) * 8;
    const bf16* bBase = Bb + (size_t)(n0 + wave * 16 + (lane >> 3)) * K
                           + ((lane & 7) ^ (lane >> 3)) * 8;

    // read-side swizzle: logical chunk c=ks*4+quad at row r lives at phys
    // chunk c^(r&7); r&7 == l15&7 for all frag rows.
    int swz = l15 & 7;
    int ck0 = (quad ^ swz) * 8;
    int ck1 = ck0 ^ 32;                             // (quad|4)^swz, *8
    int arow = (wm * 128 + l15) * 64;
    int brow = (wn * 64 + l15) * 64;

    // prologue: tile 0 fully + 3 halves of tile 1 in flight
    STAGE(0, 0); STAGE(1, 0); STAGE(2, 0); STAGE(3, 0);
    if (NT > 1) {
        STAGE(0, 1); STAGE(1, 1); STAGE(2, 1);
        asm volatile("s_waitcnt vmcnt(6)" ::: "memory");
    } else {
        asm volatile("s_waitcnt vmcnt(0)" ::: "memory");
    }
    BAR256();

    for (int t = 0; t < NT; ++t) {
        const short* Ard = &At[t & 1][0];
        const short* Brd = &Bt[t & 1][0];
        bool i1 = (t + 1 < NT), i2 = (t + 2 < NT);
        bf16x8 af[8][2], bfr[4][2];

        // ---- phase 1: Q(mh0, nh0) ----
        if (i1) STAGE(3, t + 1);
        RD_A(0, 0); RD_A(0, 1); RD_A(1, 0); RD_A(1, 1);
        RD_A(2, 0); RD_A(2, 1); RD_A(3, 0); RD_A(3, 1);
        RD_A(4, 0); RD_A(4, 1); RD_A(5, 0); RD_A(5, 1);
        RD_A(6, 0); RD_A(6, 1); RD_A(7, 0); RD_A(7, 1);
        RD_B(0, 0); RD_B(0, 1); RD_B(1, 0); RD_B(1, 1);
        BAR256(); LGKM0();
        __builtin_amdgcn_s_setprio(1);
#pragma unroll
        for (int mi = 0; mi < 4; ++mi)
#pragma unroll
            for (int ni = 0; ni < 2; ++ni)
#pragma unroll
                for (int ks = 0; ks < 2; ++ks)
                    acc[mi][ni] = __builtin_amdgcn_mfma_f32_16x16x32_bf16(
                        af[mi][ks], bfr[ni][ks], acc[mi][ni], 0, 0, 0);
        __builtin_amdgcn_s_setprio(0);
        BAR256();

        // ---- phase 2: Q(mh0, nh1) ----
        if (i2) STAGE(0, t + 2);
        RD_B(2, 0); RD_B(2, 1); RD_B(3, 0); RD_B(3, 1);
        BAR256(); LGKM0();
        __builtin_amdgcn_s_setprio(1);
#pragma unroll
        for (int mi = 0; mi < 4; ++mi)
#pragma unroll
            for (int ni = 0; ni < 2; ++ni)
#pragma unroll
                for (int ks = 0; ks < 2; ++ks)
                    acc[mi][2 + ni] = __builtin_amdgcn_mfma_f32_16x16x32_bf16(
                        af[mi][ks], bfr[2 + ni][ks], acc[mi][2 + ni], 0, 0, 0);
        __builtin_amdgcn_s_setprio(0);
        BAR256();

        // ---- phase 3: Q(mh1, nh1) ----
        if (i2) STAGE(1, t + 2);
        BAR256();
        __builtin_amdgcn_s_setprio(1);
#pragma unroll
        for (int mi = 0; mi < 4; ++mi)
#pragma unroll
            for (int ni = 0; ni < 2; ++ni)
#pragma unroll
                for (int ks = 0; ks < 2; ++ks)
                    acc[4 + mi][2 + ni] = __builtin_amdgcn_mfma_f32_16x16x32_bf16(
                        af[4 + mi][ks], bfr[2 + ni][ks], acc[4 + mi][2 + ni], 0, 0, 0);
        __builtin_amdgcn_s_setprio(0);
        BAR256();

        // ---- phase 4: Q(mh1, nh0) ----
        if (i2) STAGE(2, t + 2);
        if (i2) asm volatile("s_waitcnt vmcnt(6)" ::: "memory");
        else    asm volatile("s_waitcnt vmcnt(0)" ::: "memory");
        BAR256();
        __builtin_amdgcn_s_setprio(1);
#pragma unroll
        for (int mi = 0; mi < 4; ++mi)
#pragma unroll
            for (int ni = 0; ni < 2; ++ni)
#pragma unroll
                for (int ks = 0; ks < 2; ++ks)
                    acc[4 + mi][ni] = __builtin_amdgcn_mfma_f32_16x16x32_bf16(
                        af[4 + mi][ks], bfr[ni][ks], acc[4 + mi][ni], 0, 0, 0);
        __builtin_amdgcn_s_setprio(0);
        BAR256();
    }

    // ---- epilogue ----
#pragma unroll
    for (int ni = 0; ni < 4; ++ni) {
        int col = n0 + wn * 64 + ni * 16 + l15;
        float bv = (EPI == 1 || EPI == 2) ? bias[col] : 0.f;
#pragma unroll
        for (int mi = 0; mi < 8; ++mi) {
            int row0 = m0 + wm * 128 + mi * 16 + quad * 4;
#pragma unroll
            for (int r = 0; r < 4; ++r) {
                size_t idx = (size_t)(row0 + r) * N + col;
                float val = acc[mi][ni][r];
                if constexpr (EPI == 0) {
                    ((bf16*)Cout)[(size_t)z * sC + idx] = __float2bfloat16(val);
                } else if constexpr (EPI == 1) {
                    ((float*)Cout)[idx] = val + bv + Res[idx];
                } else {
                    val += bv;
                    val = 0.5f * val * (1.f + erff(val * 0.70710678118654752f));
                    ((bf16*)Cout)[idx] = __float2bfloat16(val);
                }
            }
        }
    }
}

// ---------------------------------------------------------------------------
// Workspace (peak 62 MB):
//   [0,16)  : hnorm bf16 -> attn bf16 (step4 out) -> mnorm bf16 (step6 out)
//   [16,18) : uvT bf16 (dead after step 2) -> qg fp32 (written step 2b)
//   [18,20) : kg fp32
//   [20,36) : hnormT bf16            -+ tbuf bf16 [20,52) after step 4
//   [36,52) : qkraw fp32 4x4MB split-K partials (dead after 2b) -> Mbuf bf16
//   [52,54) : proj_w bf16   [54,58): up_w bf16   [58,62): down_w bf16
//   h1 lives in d_out (fp32); step 8 does same-index RMW (alias-safe).
// ---------------------------------------------------------------------------
extern "C" void kernel_launch(void* const* d_in, const int* in_sizes, int n_in,
                              void* d_out, int out_size, void* d_ws, size_t ws_size,
                              hipStream_t stream) {
    const float* h           = (const float*)d_in[0];
    const float* k_base      = (const float*)d_in[1];
    const float* decay_logit = (const float*)d_in[2];
    const float* gate_logit  = (const float*)d_in[3];
    const float* alpha_logit = (const float*)d_in[4];
    const float* u           = (const float*)d_in[5];
    const float* v           = (const float*)d_in[6];
    const float* proj_w      = (const float*)d_in[7];
    const float* proj_b      = (const float*)d_in[8];
    const float* norm1_scale = (const float*)d_in[9];
    const float* norm2_scale = (const float*)d_in[10];
    const float* up_w        = (const float*)d_in[11];
    const float* up_b        = (const float*)d_in[12];
    const float* down_w      = (const float*)d_in[13];
    const float* down_b      = (const float*)d_in[14];

    const size_t MB = 1048576;
    char* ws = (char*)d_ws;
    bf16*  hnorm   = (bf16*)(ws);                  // 16 MB
    bf16*  uvT     = (bf16*)(ws + 16 * MB);        // 256 KB (dead after step 2)
    float* qg      = (float*)(ws + 16 * MB);       //  2 MB (written step 2b)
    float* kg      = (float*)(ws + 18 * MB);       //  2 MB
    bf16*  hnormT  = (bf16*)(ws + 20 * MB);        // 16 MB
    float* qkraw   = (float*)(ws + 36 * MB);       // 16 MB partials (pre-buildM)
    bf16*  Mbuf    = (bf16*)(ws + 36 * MB);        // 16 MB (step 3 out)
    bf16*  proj_wb = (bf16*)(ws + 52 * MB);        //  2 MB
    bf16*  up_wb   = (bf16*)(ws + 54 * MB);        //  4 MB
    bf16*  down_wb = (bf16*)(ws + 58 * MB);        //  4 MB
    bf16*  attn    = hnorm;                        // [0,16) after qk GEMM
    bf16*  mnorm   = hnorm;
    bf16*  tbuf    = hnormT;                       // [20,52) after step 4
    float* h1      = (float*)d_out;

    // 0. weight conversions (single launch) + uvT
    convert3_kernel<<<5 * D_ * D_ / 2048, 256, 0, stream>>>(
        proj_w, up_w, down_w, proj_wb, up_wb, down_wb);
    uvT_kernel<<<dim3(D_ / 64, 1, 2), 256, 0, stream>>>(u, v, uvT);

    // 1. h_norm = rmsnorm(h, norm1_scale)
    rmsnorm_kernel<<<B_ * W_, 256, 0, stream>>>(h, norm1_scale, hnorm);

    // 1b. hnormT[b][d][j] = hnorm[b][j][d]
    transpose_kernel<<<dim3(W_ / 64, D_ / 64, B_), 256, 0, stream>>>(hnorm, hnormT);

    // 2. qkraw[z] = hnorm @ [u|v] K-chunk z (deterministic split-K=4)
    mgemm_kernel<5, 4><<<dim3(B_ * W_ / 128, 1, 4), 512, 0, stream>>>(
        hnorm, uvT, nullptr, nullptr, qkraw, B_ * W_, 128, D_,
        0, 0, (long)B_ * W_ * 128, 0);

    // 2b. sum partials, l2norm halves, gamma^{+/-i} -> qg, kg (fp32)
    qk_epilogue_kernel<<<B_ * W_, 128, 0, stream>>>(qkraw, decay_logit, qg, kg);

    // 3. M = causal * (gate*k_base + alpha*scores)
    buildM_kernel<<<dim3(W_ / 32, W_ / 32, B_), dim3(16, 16), 0, stream>>>(
        qg, kg, k_base, gate_logit, alpha_logit, Mbuf);

    // 4. attn = M @ hnorm  (B = hnormT, batched via z, causal k-trunc)
    mgemm256_kernel<0><<<dim3(W_ / 256, D_ / 256, B_), 512, 0, stream>>>(
        Mbuf, hnormT, nullptr, nullptr, attn, W_, D_, W_,
        (long)W_ * W_, (long)W_ * D_, (long)W_ * D_, 1);

    // 5. h1 = h + attn @ proj_w^T + proj_b   -> d_out (fp32)
    mgemm256_kernel<1><<<dim3(B_ * W_ / 256, D_ / 256, 1), 512, 0, stream>>>(
        attn, proj_wb, h, proj_b, h1, B_ * W_, D_, D_, 0, 0, 0, 0);

    // 6. mnorm = rmsnorm(h1, norm2_scale)
    rmsnorm_kernel<<<B_ * W_, 256, 0, stream>>>(h1, norm2_scale, mnorm);

    // 7. t = gelu(mnorm @ up_w^T + up_b)     -> tbuf (bf16)
    mgemm256_kernel<2><<<dim3(B_ * W_ / 256, 2 * D_ / 256, 1), 512, 0, stream>>>(
        mnorm, up_wb, nullptr, up_b, tbuf, B_ * W_, 2 * D_, D_, 0, 0, 0, 0);

    // 8. out = h1 + t @ down_w^T + down_b  (h1 aliases d_out, same-idx RMW)
    mgemm256_kernel<1><<<dim3(B_ * W_ / 256, D_ / 256, 1), 512, 0, stream>>>(
        tbuf, down_wb, h1, down_b, (float*)d_out, B_ * W_, D_, 2 * D_, 0, 0, 0, 0);
}

// Round 2
// 367.272 us; speedup vs baseline: 1.1402x; 1.1402x over previous
//
#include <hip/hip_runtime.h>
#include <hip/hip_bf16.h>
#include <math.h>

#define B_ 8
#define W_ 1024
#define D_ 1024
#define R_ 64

typedef __hip_bfloat16 bf16;
typedef __attribute__((ext_vector_type(8))) short bf16x8;   // MFMA A/B frag (4 VGPRs)
typedef __attribute__((ext_vector_type(4))) float f32x4;    // MFMA C/D frag

__device__ __forceinline__ float tof(bf16 x) { return __bfloat162float(x); }
__device__ __forceinline__ short f2bs(float f) {
    bf16 b = __float2bfloat16(f);
    return *(short*)&b;
}

// async global->LDS, 16 bytes/lane; LDS dest = wave-uniform base + lane*16
__device__ __forceinline__ void async16(const void* g, void* l) {
    __builtin_amdgcn_global_load_lds(
        (const __attribute__((address_space(1))) unsigned int*)g,
        (__attribute__((address_space(3))) unsigned int*)l,
        16, 0, 0);
}

// ---------------------------------------------------------------------------
// RMSNorm: one block (256 threads) per row of D_=1024. fp32 in, bf16 out.
// ---------------------------------------------------------------------------
__global__ __launch_bounds__(256)
void rmsnorm_kernel(const float* __restrict__ src, const float* __restrict__ scale,
                    bf16* __restrict__ dst) {
    int row = blockIdx.x;
    const float* x = src + (size_t)row * D_;
    bf16* y = dst + (size_t)row * D_;
    float xv[4];
    float ss = 0.f;
#pragma unroll
    for (int it = 0; it < 4; ++it) {
        int d = threadIdx.x + it * 256;
        xv[it] = x[d];
        ss += xv[it] * xv[it];
    }
#pragma unroll
    for (int off = 32; off; off >>= 1) ss += __shfl_down(ss, off, 64);
    __shared__ float red[4];
    __shared__ float invs;
    int lane = threadIdx.x & 63, wid = threadIdx.x >> 6;
    if (lane == 0) red[wid] = ss;
    __syncthreads();
    if (threadIdx.x == 0) {
        float t = red[0] + red[1] + red[2] + red[3];
        invs = rsqrtf(t / (float)D_ + 1e-8f);
    }
    __syncthreads();
    float inv = invs;
#pragma unroll
    for (int it = 0; it < 4; ++it) {
        int d = threadIdx.x + it * 256;
        y[d] = __float2bfloat16(xv[it] * inv * scale[d]);
    }
}

// ---------------------------------------------------------------------------
// 64x64 LDS-tiled transpose: src[b][j][d] -> dst[b][d][j]  (bf16)
// ---------------------------------------------------------------------------
__global__ __launch_bounds__(256)
void transpose_kernel(const bf16* __restrict__ src, bf16* __restrict__ dst) {
    int b = blockIdx.z;
    int j0 = blockIdx.x * 64, d0 = blockIdx.y * 64;
    __shared__ short Ts[64][72];
    const bf16* S = src + (size_t)b * W_ * D_;
    bf16* Dd = dst + (size_t)b * W_ * D_;
    int tid = threadIdx.x;
    int r = tid >> 3, c = (tid & 7) * 8;
#pragma unroll
    for (int p = 0; p < 2; ++p) {
        int j = r + p * 32;
        bf16x8 vv = *(const bf16x8*)&S[(size_t)(j0 + j) * D_ + d0 + c];
#pragma unroll
        for (int e = 0; e < 8; ++e) Ts[j][c + e] = vv[e];
    }
    __syncthreads();
#pragma unroll
    for (int p = 0; p < 2; ++p) {
        int d = r + p * 32;
        bf16x8 vv;
#pragma unroll
        for (int e = 0; e < 8; ++e) vv[e] = Ts[c + e][d];
        *(bf16x8*)&Dd[(size_t)(d0 + d) * W_ + j0 + c] = vv;
    }
}

// ---------------------------------------------------------------------------
// uvT[r][d] (bf16, [128][1024]) from u[d][64] (z=0) and v[d][64] (z=1).
// ---------------------------------------------------------------------------
__global__ __launch_bounds__(256)
void uvT_kernel(const float* __restrict__ u, const float* __restrict__ v,
                bf16* __restrict__ uvT) {
    int g = blockIdx.z;
    int d0 = blockIdx.x * 64;
    const float* src = g ? v : u;
    __shared__ float Ts[64][65];
    int tid = threadIdx.x;
#pragma unroll
    for (int e = 0; e < 16; ++e) {
        int idx = tid + e * 256;
        int drow = idx >> 6, rcol = idx & 63;
        Ts[drow][rcol] = src[(size_t)(d0 + drow) * 64 + rcol];
    }
    __syncthreads();
#pragma unroll
    for (int e = 0; e < 16; ++e) {
        int idx = tid + e * 256;
        int orow = idx >> 6, ocol = idx & 63;
        uvT[(size_t)(g * 64 + orow) * D_ + d0 + ocol] = __float2bfloat16(Ts[ocol][orow]);
    }
}

// ---------------------------------------------------------------------------
// fp32 -> bf16 convert of the three weight matrices in ONE launch.
// ---------------------------------------------------------------------------
__global__ __launch_bounds__(256)
void convert3_kernel(const float* __restrict__ proj, const float* __restrict__ up,
                     const float* __restrict__ down,
                     bf16* __restrict__ projb, bf16* __restrict__ upb,
                     bf16* __restrict__ downb) {
    size_t idx = ((size_t)blockIdx.x * 256 + threadIdx.x) * 8;
    const size_t DD = (size_t)D_ * D_;
    const float* src; bf16* dst; size_t off;
    if (idx < DD)          { src = proj; dst = projb; off = idx; }
    else if (idx < 3 * DD) { src = up;   dst = upb;   off = idx - DD; }
    else                   { src = down; dst = downb; off = idx - 3 * DD; }
    float4 f0 = *(const float4*)(src + off);
    float4 f1 = *(const float4*)(src + off + 4);
    bf16x8 p;
    p[0] = f2bs(f0.x); p[1] = f2bs(f0.y); p[2] = f2bs(f0.z); p[3] = f2bs(f0.w);
    p[4] = f2bs(f1.x); p[5] = f2bs(f1.y); p[6] = f2bs(f1.z); p[7] = f2bs(f1.w);
    *(bf16x8*)(dst + off) = p;
}

// ---------------------------------------------------------------------------
// qk epilogue: sum SK=4 fp32 partials, l2norm halves, gamma^{+/-i} -> qg, kg.
// ---------------------------------------------------------------------------
__global__ __launch_bounds__(128)
void qk_epilogue_kernel(const float* __restrict__ qkraw,
                        const float* __restrict__ decay_logit,
                        float* __restrict__ qg, float* __restrict__ kg) {
    int row = blockIdx.x;          // b*W + i
    int i = row & (W_ - 1);
    int t = threadIdx.x;
    int r = t & 63;
    bool isK = t >= 64;
    const size_t PS = (size_t)B_ * W_ * 128;   // partial stride
    size_t off = (size_t)row * 128 + t;
    float val = qkraw[off] + qkraw[PS + off] + qkraw[2 * PS + off] + qkraw[3 * PS + off];
    float sq = val * val;
#pragma unroll
    for (int o = 32; o; o >>= 1) sq += __shfl_xor(sq, o, 64);
    val = val / fmaxf(sqrtf(sq), 1e-8f);

    float dl = decay_logit[r];
    float gamma = 0.15f + 0.85f * (1.f / (1.f + expf(-dl)));
    float lg = logf(gamma);
    float e = isK ? expf(-(float)i * lg) : expf((float)i * lg);
    float o = val * e;
    if (isK) kg[(size_t)row * R_ + r] = o;
    else     qg[(size_t)row * R_ + r] = o;
}

// ---------------------------------------------------------------------------
// M[b,i,j] = (j<=i) ? gate*k_base[i,j] + alpha * dot(qg[b,i,:], kg[b,j,:]) : 0
// ---------------------------------------------------------------------------
__global__ __launch_bounds__(256)
void buildM_kernel(const float* __restrict__ qg, const float* __restrict__ kg,
                   const float* __restrict__ k_base,
                   const float* __restrict__ gate_logit,
                   const float* __restrict__ alpha_logit,
                   bf16* __restrict__ M) {
    int b = blockIdx.z;
    int ti = blockIdx.y, tj = blockIdx.x;
    int i0 = ti * 32, j0 = tj * 32;
    int tx = threadIdx.x, ty = threadIdx.y;
    bf16* Mb = M + (size_t)b * W_ * W_;
    const bf16 zero = __float2bfloat16(0.f);

    if (tj > ti) {
#pragma unroll
        for (int a = 0; a < 2; ++a)
#pragma unroll
            for (int c = 0; c < 2; ++c)
                Mb[(size_t)(i0 + ty * 2 + a) * W_ + (j0 + tx * 2 + c)] = zero;
        return;
    }

    __shared__ float Qs[32][65];
    __shared__ float Ks[32][65];
    int tid = ty * 16 + tx;
    for (int e = tid; e < 32 * 64; e += 256) {
        int rr = e & 63, row = e >> 6;
        Qs[row][rr] = qg[((size_t)b * W_ + i0 + row) * R_ + rr];
        Ks[row][rr] = kg[((size_t)b * W_ + j0 + row) * R_ + rr];
    }
    __syncthreads();

    float acc[2][2] = {{0.f, 0.f}, {0.f, 0.f}};
#pragma unroll 8
    for (int r = 0; r < 64; ++r) {
        float qa = Qs[ty * 2 + 0][r], qb = Qs[ty * 2 + 1][r];
        float ka = Ks[tx * 2 + 0][r], kb = Ks[tx * 2 + 1][r];
        acc[0][0] += qa * ka; acc[0][1] += qa * kb;
        acc[1][0] += qb * ka; acc[1][1] += qb * kb;
    }

    float gate  = 1.f / (1.f + expf(-(*gate_logit)));
    float alpha = 1.f / (1.f + expf(-(*alpha_logit)));  // ALPHA_CAP = 1
#pragma unroll
    for (int a = 0; a < 2; ++a) {
#pragma unroll
        for (int c = 0; c < 2; ++c) {
            int i = i0 + ty * 2 + a, j = j0 + tx * 2 + c;
            float vkb = k_base[(size_t)i * W_ + j];
            float out = (j <= i) ? (gate * vkb + alpha * acc[a][c]) : 0.f;
            Mb[(size_t)i * W_ + j] = __float2bfloat16(out);
        }
    }
}

// ---------------------------------------------------------------------------
// MFMA GEMM: C[m,n] = sum_k A[m,k]*B[n,k]  (A, B bf16, k-major)
// BM=BN=128, BK=32 — proven round-9 geometry (tile/swizzle/epilogue
// unchanged). *** Round-14 change: LATENCY DEPTH. Evidence r13: both the
// 2-phase (this kernel) and an 8-phase 256^2 port sit at the SAME ~1.7
// TF/CU and ~5.4 staged-B/cyc/CU with FETCH==ideal and 0 bank conflicts ->
// exposed load latency, not bandwidth/conflicts/schedule-phases. Old
// structure drained vmcnt(0) at every __syncthreads (~2KB in flight/wave).
// Now: 4 LDS buffers (64 KB/block, still 2 blocks/CU), loads issued 3
// tiles AHEAD, ONE raw s_barrier per iter (no compiler vmcnt0+lgkm0
// drain), counted vmcnt(4) steady-state (tail: 2,0). In-flight/CU 32->96KB.
// Safety: STAGE(t+3) overwrites buf (t-1)&3, whose reads finished before
// every wave reached iter t's barrier (reads -> lgkm wait -> MFMA issue ->
// barrier arrival is program order). Each wave's vmcnt(4) covers its OWN
// tile-t loads before the barrier; barrier publishes the tile.
// Wave w (0-7): subtile rows wy*32 (wy=w>>1), cols wx*64 (wx=w&1) -> 2x4
// MFMA frags. Staging: wave w stages A rows [w*16,w*16+16) and B rows
// [w*16,w*16+16), 1 async16 each, XOR-swizzled (conflict-free).
// Grid XCD-TRANSPOSED: x = M-stripe (count % 8 == 0), y = N-block.
// SK>1: z = K-chunk, EPI must be 5.  SK==1: z = batch.
// EPI 0: Cout bf16 = acc                      (batched store via sC)
// EPI 1: Cout fp32 = acc + bias[n] + Res[idx] (Res may alias Cout, same-idx)
// EPI 2: Cout bf16 = gelu_exact(acc + bias[n])
// EPI 5: Cout fp32 partial at z*sC            (deterministic split-K)
// ---------------------------------------------------------------------------
template<int EPI, int SK>
__global__ __launch_bounds__(512)
void mgemm_kernel(const bf16* __restrict__ A, const bf16* __restrict__ Bm,
                  const float* __restrict__ Res, const float* __restrict__ bias,
                  void* __restrict__ Cout,
                  int M, int N, int K,
                  long sA, long sB, long sC, int causal) {
    __shared__ __align__(16) short At[4][128 * 32];   // 4-deep, 32 KB
    __shared__ __align__(16) short Bt[4][128 * 32];   // 4-deep, 32 KB
    int z = blockIdx.z;
    const bf16* Ab = (SK > 1) ? A : A + (size_t)z * sA;
    const bf16* Bb = (SK > 1) ? Bm : Bm + (size_t)z * sB;
    int kchunk = K / SK;
    int kbeg = (SK > 1) ? z * kchunk : 0;
    int m0 = blockIdx.x * 128, n0 = blockIdx.y * 128;   // transposed grid
    int tid = threadIdx.x;
    int lane = tid & 63, wave = tid >> 6;               // wave 0..7
    int wy = wave >> 1, wx = wave & 1;
    int quad = lane >> 4, l15 = lane & 15;

    f32x4 acc[2][4];
#pragma unroll
    for (int i = 0; i < 2; ++i)
#pragma unroll
        for (int j = 0; j < 4; ++j)
            acc[i][j] = (f32x4){0.f, 0.f, 0.f, 0.f};

    int kend = kbeg + kchunk;
    if (SK == 1 && causal) kend = (m0 + 128 < K) ? m0 + 128 : K;
    int nIter = (kend - kbeg) >> 5;

    // staging: wave w covers rows [w*16, w*16+16); lane -> row w*16+(lane>>2),
    // 16B chunk slot lane&3, source chunk XOR-swizzled (b128 reads 2-way max).
    int srcChunk = ((lane & 3) ^ ((lane >> 3) & 3)) * 8;
    size_t rowA = (size_t)(m0 + wave * 16 + (lane >> 2)) * K;
    size_t rowB = (size_t)(n0 + wave * 16 + (lane >> 2)) * K;
    const bf16* aP = Ab + rowA + srcChunk + kbeg;
    const bf16* bP = Bb + rowB + srcChunk + kbeg;
    short* aDst0 = &At[0][0] + wave * 512;
    short* bDst0 = &Bt[0][0] + wave * 512;

    int rswz = (quad ^ ((l15 >> 1) & 3)) * 8;

    // prologue: issue tiles 0..2 (3 tiles deep); NO wait yet.
    int npro = (nIter < 3) ? nIter : 3;
    for (int p = 0; p < npro; ++p) {
        async16(aP, aDst0 + p * 4096);
        async16(bP, bDst0 + p * 4096);
        aP += 32; bP += 32;
    }

    for (int it = 0; it < nIter; ++it) {
        // counted wait: tiles issued beyond `it` = min(2, nIter-1-it) -> 2
        // loads each. Guarantees tile `it` (ours) has landed.
        int ahead = nIter - 1 - it;
        if (ahead >= 2)      asm volatile("s_waitcnt vmcnt(4)" ::: "memory");
        else if (ahead == 1) asm volatile("s_waitcnt vmcnt(2)" ::: "memory");
        else                 asm volatile("s_waitcnt vmcnt(0)" ::: "memory");
        __builtin_amdgcn_sched_barrier(0);
        __builtin_amdgcn_s_barrier();       // publishes tile `it`; all reads of
        __builtin_amdgcn_sched_barrier(0);  // tile it-1 are complete block-wide

        if (it + 3 < nIter) {               // issue tile it+3 into buf (it+3)&3
            int slot = (it + 3) & 3;
            async16(aP, aDst0 + slot * 4096);
            async16(bP, bDst0 + slot * 4096);
            aP += 32; bP += 32;
        }

        const short* Ard = &At[it & 3][0];
        const short* Brd = &Bt[it & 3][0];
        bf16x8 af[2], bfr[4];
#pragma unroll
        for (int mi = 0; mi < 2; ++mi)
            af[mi] = *(const bf16x8*)&Ard[(wy * 32 + mi * 16 + l15) * 32 + rswz];
#pragma unroll
        for (int ni = 0; ni < 4; ++ni)
            bfr[ni] = *(const bf16x8*)&Brd[(wx * 64 + ni * 16 + l15) * 32 + rswz];
#pragma unroll
        for (int mi = 0; mi < 2; ++mi)
#pragma unroll
            for (int ni = 0; ni < 4; ++ni)
                acc[mi][ni] = __builtin_amdgcn_mfma_f32_16x16x32_bf16(
                    af[mi], bfr[ni], acc[mi][ni], 0, 0, 0);
        // no trailing barrier: next iter's top barrier covers buffer reuse
        // (nearest overwrite of buf it&3 is STAGE(it+4) issued at iter it+1,
        // after that barrier).
    }

    // ---- epilogue ----
#pragma unroll
    for (int ni = 0; ni < 4; ++ni) {
        int col = n0 + wx * 64 + ni * 16 + l15;
        float bv = (EPI == 1 || EPI == 2) ? bias[col] : 0.f;
#pragma unroll
        for (int mi = 0; mi < 2; ++mi) {
            int row0 = m0 + wy * 32 + mi * 16 + quad * 4;
#pragma unroll
            for (int r = 0; r < 4; ++r) {
                size_t idx = (size_t)(row0 + r) * N + col;
                float val = acc[mi][ni][r];
                if constexpr (EPI == 0) {
                    ((bf16*)Cout)[(size_t)z * sC + idx] = __float2bfloat16(val);
                } else if constexpr (EPI == 1) {
                    ((float*)Cout)[idx] = val + bv + Res[idx];
                } else if constexpr (EPI == 2) {
                    val += bv;
                    val = 0.5f * val * (1.f + erff(val * 0.70710678118654752f));
                    ((bf16*)Cout)[idx] = __float2bfloat16(val);
                } else {
                    ((float*)Cout)[(size_t)z * sC + idx] = val;
                }
            }
        }
    }
}

// ---------------------------------------------------------------------------
// Workspace (peak 62 MB):
//   [0,16)  : hnorm bf16 -> attn bf16 (step4 out) -> mnorm bf16 (step6 out)
//   [16,18) : uvT bf16 (dead after step 2) -> qg fp32 (written step 2b)
//   [18,20) : kg fp32
//   [20,36) : hnormT bf16            -+ tbuf bf16 [20,52) after step 4
//   [36,52) : qkraw fp32 4x4MB split-K partials (dead after 2b) -> Mbuf bf16
//   [52,54) : proj_w bf16   [54,58): up_w bf16   [58,62): down_w bf16
//   h1 lives in d_out (fp32); step 8 does same-index RMW (alias-safe).
// ---------------------------------------------------------------------------
extern "C" void kernel_launch(void* const* d_in, const int* in_sizes, int n_in,
                              void* d_out, int out_size, void* d_ws, size_t ws_size,
                              hipStream_t stream) {
    const float* h           = (const float*)d_in[0];
    const float* k_base      = (const float*)d_in[1];
    const float* decay_logit = (const float*)d_in[2];
    const float* gate_logit  = (const float*)d_in[3];
    const float* alpha_logit = (const float*)d_in[4];
    const float* u           = (const float*)d_in[5];
    const float* v           = (const float*)d_in[6];
    const float* proj_w      = (const float*)d_in[7];
    const float* proj_b      = (const float*)d_in[8];
    const float* norm1_scale = (const float*)d_in[9];
    const float* norm2_scale = (const float*)d_in[10];
    const float* up_w        = (const float*)d_in[11];
    const float* up_b        = (const float*)d_in[12];
    const float* down_w      = (const float*)d_in[13];
    const float* down_b      = (const float*)d_in[14];

    const size_t MB = 1048576;
    char* ws = (char*)d_ws;
    bf16*  hnorm   = (bf16*)(ws);                  // 16 MB
    bf16*  uvT     = (bf16*)(ws + 16 * MB);        // 256 KB (dead after step 2)
    float* qg      = (float*)(ws + 16 * MB);       //  2 MB (written step 2b)
    float* kg      = (float*)(ws + 18 * MB);       //  2 MB
    bf16*  hnormT  = (bf16*)(ws + 20 * MB);        // 16 MB
    float* qkraw   = (float*)(ws + 36 * MB);       // 16 MB partials (pre-buildM)
    bf16*  Mbuf    = (bf16*)(ws + 36 * MB);        // 16 MB (step 3 out)
    bf16*  proj_wb = (bf16*)(ws + 52 * MB);        //  2 MB
    bf16*  up_wb   = (bf16*)(ws + 54 * MB);        //  4 MB
    bf16*  down_wb = (bf16*)(ws + 58 * MB);        //  4 MB
    bf16*  attn    = hnorm;                        // [0,16) after qk GEMM
    bf16*  mnorm   = hnorm;
    bf16*  tbuf    = hnormT;                       // [20,52) after step 4
    float* h1      = (float*)d_out;

    // 0. weight conversions (single launch) + uvT
    convert3_kernel<<<5 * D_ * D_ / 2048, 256, 0, stream>>>(
        proj_w, up_w, down_w, proj_wb, up_wb, down_wb);
    uvT_kernel<<<dim3(D_ / 64, 1, 2), 256, 0, stream>>>(u, v, uvT);

    // 1. h_norm = rmsnorm(h, norm1_scale)
    rmsnorm_kernel<<<B_ * W_, 256, 0, stream>>>(h, norm1_scale, hnorm);

    // 1b. hnormT[b][d][j] = hnorm[b][j][d]
    transpose_kernel<<<dim3(W_ / 64, D_ / 64, B_), 256, 0, stream>>>(hnorm, hnormT);

    // 2. qkraw[z] = hnorm @ [u|v] K-chunk z (deterministic split-K=4)
    mgemm_kernel<5, 4><<<dim3(B_ * W_ / 128, 1, 4), 512, 0, stream>>>(
        hnorm, uvT, nullptr, nullptr, qkraw, B_ * W_, 128, D_,
        0, 0, (long)B_ * W_ * 128, 0);

    // 2b. sum partials, l2norm halves, gamma^{+/-i} -> qg, kg (fp32)
    qk_epilogue_kernel<<<B_ * W_, 128, 0, stream>>>(qkraw, decay_logit, qg, kg);

    // 3. M = causal * (gate*k_base + alpha*scores)
    buildM_kernel<<<dim3(W_ / 32, W_ / 32, B_), dim3(16, 16), 0, stream>>>(
        qg, kg, k_base, gate_logit, alpha_logit, Mbuf);

    // 4. attn = M @ hnorm  (B = hnormT, batched via z, causal k-trunc)
    mgemm_kernel<0, 1><<<dim3(W_ / 128, D_ / 128, B_), 512, 0, stream>>>(
        Mbuf, hnormT, nullptr, nullptr, attn, W_, D_, W_,
        (long)W_ * W_, (long)W_ * D_, (long)W_ * D_, 1);

    // 5. h1 = h + attn @ proj_w^T + proj_b   -> d_out (fp32)
    mgemm_kernel<1, 1><<<dim3(B_ * W_ / 128, D_ / 128, 1), 512, 0, stream>>>(
        attn, proj_wb, h, proj_b, h1, B_ * W_, D_, D_, 0, 0, 0, 0);

    // 6. mnorm = rmsnorm(h1, norm2_scale)
    rmsnorm_kernel<<<B_ * W_, 256, 0, stream>>>(h1, norm2_scale, mnorm);

    // 7. t = gelu(mnorm @ up_w^T + up_b)     -> tbuf (bf16)
    mgemm_kernel<2, 1><<<dim3(B_ * W_ / 128, 2 * D_ / 128, 1), 512, 0, stream>>>(
        mnorm, up_wb, nullptr, up_b, tbuf, B_ * W_, 2 * D_, D_, 0, 0, 0, 0);

    // 8. out = h1 + t @ down_w^T + down_b  (h1 aliases d_out, same-idx RMW)
    mgemm_kernel<1, 1><<<dim3(B_ * W_ / 128, D_ / 128, 1), 512, 0, stream>>>(
        tbuf, down_wb, h1, down_b, (float*)d_out, B_ * W_, D_, 2 * D_, 0, 0, 0, 0);
}

// Round 3
// 350.147 us; speedup vs baseline: 1.1960x; 1.0489x over previous
//
#include <hip/hip_runtime.h>
#include <hip/hip_bf16.h>
#include <math.h>

#define B_ 8
#define W_ 1024
#define D_ 1024
#define R_ 64

typedef __hip_bfloat16 bf16;
typedef __attribute__((ext_vector_type(8))) short bf16x8;   // MFMA A/B frag (4 VGPRs)
typedef __attribute__((ext_vector_type(4))) float f32x4;    // MFMA C/D frag

__device__ __forceinline__ float tof(bf16 x) { return __bfloat162float(x); }
__device__ __forceinline__ short f2bs(float f) {
    bf16 b = __float2bfloat16(f);
    return *(short*)&b;
}

// async global->LDS, 16 bytes/lane; LDS dest = wave-uniform base + lane*16
__device__ __forceinline__ void async16(const void* g, void* l) {
    __builtin_amdgcn_global_load_lds(
        (const __attribute__((address_space(1))) unsigned int*)g,
        (__attribute__((address_space(3))) unsigned int*)l,
        16, 0, 0);
}

// ---------------------------------------------------------------------------
// RMSNorm: one block (256 threads) per row of D_=1024. fp32 in, bf16 out.
// ---------------------------------------------------------------------------
__global__ __launch_bounds__(256)
void rmsnorm_kernel(const float* __restrict__ src, const float* __restrict__ scale,
                    bf16* __restrict__ dst) {
    int row = blockIdx.x;
    const float* x = src + (size_t)row * D_;
    bf16* y = dst + (size_t)row * D_;
    float xv[4];
    float ss = 0.f;
#pragma unroll
    for (int it = 0; it < 4; ++it) {
        int d = threadIdx.x + it * 256;
        xv[it] = x[d];
        ss += xv[it] * xv[it];
    }
#pragma unroll
    for (int off = 32; off; off >>= 1) ss += __shfl_down(ss, off, 64);
    __shared__ float red[4];
    __shared__ float invs;
    int lane = threadIdx.x & 63, wid = threadIdx.x >> 6;
    if (lane == 0) red[wid] = ss;
    __syncthreads();
    if (threadIdx.x == 0) {
        float t = red[0] + red[1] + red[2] + red[3];
        invs = rsqrtf(t / (float)D_ + 1e-8f);
    }
    __syncthreads();
    float inv = invs;
#pragma unroll
    for (int it = 0; it < 4; ++it) {
        int d = threadIdx.x + it * 256;
        y[d] = __float2bfloat16(xv[it] * inv * scale[d]);
    }
}

// ---------------------------------------------------------------------------
// 64x64 LDS-tiled transpose: src[b][j][d] -> dst[b][d][j]  (bf16)
// ---------------------------------------------------------------------------
__global__ __launch_bounds__(256)
void transpose_kernel(const bf16* __restrict__ src, bf16* __restrict__ dst) {
    int b = blockIdx.z;
    int j0 = blockIdx.x * 64, d0 = blockIdx.y * 64;
    __shared__ short Ts[64][72];
    const bf16* S = src + (size_t)b * W_ * D_;
    bf16* Dd = dst + (size_t)b * W_ * D_;
    int tid = threadIdx.x;
    int r = tid >> 3, c = (tid & 7) * 8;
#pragma unroll
    for (int p = 0; p < 2; ++p) {
        int j = r + p * 32;
        bf16x8 vv = *(const bf16x8*)&S[(size_t)(j0 + j) * D_ + d0 + c];
#pragma unroll
        for (int e = 0; e < 8; ++e) Ts[j][c + e] = vv[e];
    }
    __syncthreads();
#pragma unroll
    for (int p = 0; p < 2; ++p) {
        int d = r + p * 32;
        bf16x8 vv;
#pragma unroll
        for (int e = 0; e < 8; ++e) vv[e] = Ts[c + e][d];
        *(bf16x8*)&Dd[(size_t)(d0 + d) * W_ + j0 + c] = vv;
    }
}

// ---------------------------------------------------------------------------
// uvT[r][d] (bf16, [128][1024]) from u[d][64] (z=0) and v[d][64] (z=1).
// ---------------------------------------------------------------------------
__global__ __launch_bounds__(256)
void uvT_kernel(const float* __restrict__ u, const float* __restrict__ v,
                bf16* __restrict__ uvT) {
    int g = blockIdx.z;
    int d0 = blockIdx.x * 64;
    const float* src = g ? v : u;
    __shared__ float Ts[64][65];
    int tid = threadIdx.x;
#pragma unroll
    for (int e = 0; e < 16; ++e) {
        int idx = tid + e * 256;
        int drow = idx >> 6, rcol = idx & 63;
        Ts[drow][rcol] = src[(size_t)(d0 + drow) * 64 + rcol];
    }
    __syncthreads();
#pragma unroll
    for (int e = 0; e < 16; ++e) {
        int idx = tid + e * 256;
        int orow = idx >> 6, ocol = idx & 63;
        uvT[(size_t)(g * 64 + orow) * D_ + d0 + ocol] = __float2bfloat16(Ts[ocol][orow]);
    }
}

// ---------------------------------------------------------------------------
// fp32 -> bf16 convert of the three weight matrices in ONE launch.
// ---------------------------------------------------------------------------
__global__ __launch_bounds__(256)
void convert3_kernel(const float* __restrict__ proj, const float* __restrict__ up,
                     const float* __restrict__ down,
                     bf16* __restrict__ projb, bf16* __restrict__ upb,
                     bf16* __restrict__ downb) {
    size_t idx = ((size_t)blockIdx.x * 256 + threadIdx.x) * 8;
    const size_t DD = (size_t)D_ * D_;
    const float* src; bf16* dst; size_t off;
    if (idx < DD)          { src = proj; dst = projb; off = idx; }
    else if (idx < 3 * DD) { src = up;   dst = upb;   off = idx - DD; }
    else                   { src = down; dst = downb; off = idx - 3 * DD; }
    float4 f0 = *(const float4*)(src + off);
    float4 f1 = *(const float4*)(src + off + 4);
    bf16x8 p;
    p[0] = f2bs(f0.x); p[1] = f2bs(f0.y); p[2] = f2bs(f0.z); p[3] = f2bs(f0.w);
    p[4] = f2bs(f1.x); p[5] = f2bs(f1.y); p[6] = f2bs(f1.z); p[7] = f2bs(f1.w);
    *(bf16x8*)(dst + off) = p;
}

// ---------------------------------------------------------------------------
// qk epilogue: sum SK=4 fp32 partials, l2norm halves, gamma^{+/-i} -> qg, kg.
// ---------------------------------------------------------------------------
__global__ __launch_bounds__(128)
void qk_epilogue_kernel(const float* __restrict__ qkraw,
                        const float* __restrict__ decay_logit,
                        float* __restrict__ qg, float* __restrict__ kg) {
    int row = blockIdx.x;          // b*W + i
    int i = row & (W_ - 1);
    int t = threadIdx.x;
    int r = t & 63;
    bool isK = t >= 64;
    const size_t PS = (size_t)B_ * W_ * 128;   // partial stride
    size_t off = (size_t)row * 128 + t;
    float val = qkraw[off] + qkraw[PS + off] + qkraw[2 * PS + off] + qkraw[3 * PS + off];
    float sq = val * val;
#pragma unroll
    for (int o = 32; o; o >>= 1) sq += __shfl_xor(sq, o, 64);
    val = val / fmaxf(sqrtf(sq), 1e-8f);

    float dl = decay_logit[r];
    float gamma = 0.15f + 0.85f * (1.f / (1.f + expf(-dl)));
    float lg = logf(gamma);
    float e = isK ? expf(-(float)i * lg) : expf((float)i * lg);
    float o = val * e;
    if (isK) kg[(size_t)row * R_ + r] = o;
    else     qg[(size_t)row * R_ + r] = o;
}

// ---------------------------------------------------------------------------
// M[b,i,j] = (j<=i) ? gate*k_base[i,j] + alpha * dot(qg[b,i,:], kg[b,j,:]) : 0
// ---------------------------------------------------------------------------
__global__ __launch_bounds__(256)
void buildM_kernel(const float* __restrict__ qg, const float* __restrict__ kg,
                   const float* __restrict__ k_base,
                   const float* __restrict__ gate_logit,
                   const float* __restrict__ alpha_logit,
                   bf16* __restrict__ M) {
    int b = blockIdx.z;
    int ti = blockIdx.y, tj = blockIdx.x;
    int i0 = ti * 32, j0 = tj * 32;
    int tx = threadIdx.x, ty = threadIdx.y;
    bf16* Mb = M + (size_t)b * W_ * W_;
    const bf16 zero = __float2bfloat16(0.f);

    if (tj > ti) {
#pragma unroll
        for (int a = 0; a < 2; ++a)
#pragma unroll
            for (int c = 0; c < 2; ++c)
                Mb[(size_t)(i0 + ty * 2 + a) * W_ + (j0 + tx * 2 + c)] = zero;
        return;
    }

    __shared__ float Qs[32][65];
    __shared__ float Ks[32][65];
    int tid = ty * 16 + tx;
    for (int e = tid; e < 32 * 64; e += 256) {
        int rr = e & 63, row = e >> 6;
        Qs[row][rr] = qg[((size_t)b * W_ + i0 + row) * R_ + rr];
        Ks[row][rr] = kg[((size_t)b * W_ + j0 + row) * R_ + rr];
    }
    __syncthreads();

    float acc[2][2] = {{0.f, 0.f}, {0.f, 0.f}};
#pragma unroll 8
    for (int r = 0; r < 64; ++r) {
        float qa = Qs[ty * 2 + 0][r], qb = Qs[ty * 2 + 1][r];
        float ka = Ks[tx * 2 + 0][r], kb = Ks[tx * 2 + 1][r];
        acc[0][0] += qa * ka; acc[0][1] += qa * kb;
        acc[1][0] += qb * ka; acc[1][1] += qb * kb;
    }

    float gate  = 1.f / (1.f + expf(-(*gate_logit)));
    float alpha = 1.f / (1.f + expf(-(*alpha_logit)));  // ALPHA_CAP = 1
#pragma unroll
    for (int a = 0; a < 2; ++a) {
#pragma unroll
        for (int c = 0; c < 2; ++c) {
            int i = i0 + ty * 2 + a, j = j0 + tx * 2 + c;
            float vkb = k_base[(size_t)i * W_ + j];
            float out = (j <= i) ? (gate * vkb + alpha * acc[a][c]) : 0.f;
            Mb[(size_t)i * W_ + j] = __float2bfloat16(out);
        }
    }
}

// ---------------------------------------------------------------------------
// MFMA GEMM helpers (round-15)
// ---------------------------------------------------------------------------
#define BAR() do { __builtin_amdgcn_sched_barrier(0); \
                   __builtin_amdgcn_s_barrier(); \
                   __builtin_amdgcn_sched_barrier(0); } while (0)

__device__ __forceinline__ void mfma8(const bf16x8 (&fa)[2], const bf16x8 (&fb)[4],
                                      f32x4 (&acc)[2][4]) {
#pragma unroll
    for (int mi = 0; mi < 2; ++mi)
#pragma unroll
        for (int ni = 0; ni < 4; ++ni)
            acc[mi][ni] = __builtin_amdgcn_mfma_f32_16x16x32_bf16(
                fa[mi], fb[ni], acc[mi][ni], 0, 0, 0);
}

__device__ __forceinline__ void readf(const short* At0, const short* Bt0, int slot,
                                      const int (&ao)[2], const int (&bo)[4],
                                      bf16x8 (&fa)[2], bf16x8 (&fb)[4]) {
    const short* Ard = At0 + slot * 4096;
    const short* Brd = Bt0 + slot * 4096;
#pragma unroll
    for (int mi = 0; mi < 2; ++mi) fa[mi] = *(const bf16x8*)&Ard[ao[mi]];
#pragma unroll
    for (int ni = 0; ni < 4; ++ni) fb[ni] = *(const bf16x8*)&Brd[bo[ni]];
}

// ---------------------------------------------------------------------------
// MFMA GEMM: C[m,n] = sum_k A[m,k]*B[n,k]  (A, B bf16, k-major)
// BM=BN=128, BK=32 — proven geometry (tile/swizzle/epilogue unchanged).
// *** Round-15 change: REGISTER FRAG PREFETCH + 5-slot LDS ring. Evidence
// r14: depth-3 counted-vmcnt gave 80->62us (MfmaUtil 22%), but no pipe
// saturated: per iter the chain barrier -> 6x ds_read_b128 -> lgkm wait ->
// MFMA convoys all 16 waves (LDS ~65%, MFMA ~27%, VALU 34%). Now frags for
// tile t are ds_read at iter t-1 (double-buffered reg sets, static
// indexing), so MFMA issues immediately after the barrier and overlaps the
// current iter's ds_reads in the LDS pipe.
// Ring: 5 slots x 16 KB = 80 KB/block (2 blocks/CU = 160 KB exact).
// Iter t: vmcnt(4) [tile t+1 landed: staged thru t+3, allow t+2,t+3 = 4
// loads] -> barrier [publishes t+1] -> stage tile t+4 -> slot (t+4)%5 ->
// MFMA(frags[t]) -> prefetch frags[t+1] from slot (t+1)%5.
// Slot overwrite: stage(t+4) hits slot (t-1)%5; its frags were read at
// iter t-2, two barriers before the stage issues. Safe.
// Tail (4 iters, nIter always multiple of 4 so parity is fixed):
// vmcnt(4),(2),(0),none; no stages. Prologue: stage tiles 0..3, vmcnt(6)
// [tile 0 landed], barrier, read tile-0 frags.
// REQUIRES nIter >= 4 (K multiple of 128: all call sites satisfy).
// __launch_bounds__(512,4): pin VGPR<=128 so 2 blocks (16 waves) stay
// resident; est ~105 (32 acc + 48 frags + addr).
// Wave w (0-7): subtile rows wy*32 (wy=w>>1), cols wx*64 (wx=w&1) -> 2x4
// MFMA frags. Staging: wave w stages A rows [w*16,w*16+16) and B rows
// [w*16,w*16+16), 1 async16 each, XOR-swizzled (conflict-free).
// Grid XCD-TRANSPOSED: x = M-stripe (count % 8 == 0), y = N-block.
// SK>1: z = K-chunk, EPI must be 5.  SK==1: z = batch.
// EPI 0: Cout bf16 = acc                      (batched store via sC)
// EPI 1: Cout fp32 = acc + bias[n] + Res[idx] (Res may alias Cout, same-idx)
// EPI 2: Cout bf16 = gelu_exact(acc + bias[n])
// EPI 5: Cout fp32 partial at z*sC            (deterministic split-K)
// ---------------------------------------------------------------------------
template<int EPI, int SK>
__global__ __launch_bounds__(512, 4)
void mgemm_kernel(const bf16* __restrict__ A, const bf16* __restrict__ Bm,
                  const float* __restrict__ Res, const float* __restrict__ bias,
                  void* __restrict__ Cout,
                  int M, int N, int K,
                  long sA, long sB, long sC, int causal) {
    __shared__ __align__(16) short At[5][128 * 32];   // 5-slot ring, 40 KB
    __shared__ __align__(16) short Bt[5][128 * 32];   // 5-slot ring, 40 KB
    int z = blockIdx.z;
    const bf16* Ab = (SK > 1) ? A : A + (size_t)z * sA;
    const bf16* Bb = (SK > 1) ? Bm : Bm + (size_t)z * sB;
    int kchunk = K / SK;
    int kbeg = (SK > 1) ? z * kchunk : 0;
    int m0 = blockIdx.x * 128, n0 = blockIdx.y * 128;   // transposed grid
    int tid = threadIdx.x;
    int lane = tid & 63, wave = tid >> 6;               // wave 0..7
    int wy = wave >> 1, wx = wave & 1;
    int quad = lane >> 4, l15 = lane & 15;

    f32x4 acc[2][4];
#pragma unroll
    for (int i = 0; i < 2; ++i)
#pragma unroll
        for (int j = 0; j < 4; ++j)
            acc[i][j] = (f32x4){0.f, 0.f, 0.f, 0.f};

    int kend = kbeg + kchunk;
    if (SK == 1 && causal) kend = (m0 + 128 < K) ? m0 + 128 : K;
    int nIter = (kend - kbeg) >> 5;                     // multiple of 4, >= 4

    // staging: wave w covers rows [w*16, w*16+16); lane -> row w*16+(lane>>2),
    // 16B chunk slot lane&3, source chunk XOR-swizzled (b128 reads 2-way max).
    int srcChunk = ((lane & 3) ^ ((lane >> 3) & 3)) * 8;
    size_t rowA = (size_t)(m0 + wave * 16 + (lane >> 2)) * K;
    size_t rowB = (size_t)(n0 + wave * 16 + (lane >> 2)) * K;
    const bf16* aP = Ab + rowA + srcChunk + kbeg;
    const bf16* bP = Bb + rowB + srcChunk + kbeg;
    short* aDst = &At[0][0] + wave * 512;
    short* bDst = &Bt[0][0] + wave * 512;

    // read-side offsets (within a slot): XOR swizzle matches staging.
    int rswz = (quad ^ ((l15 >> 1) & 3)) * 8;
    int ao[2], bo[4];
#pragma unroll
    for (int mi = 0; mi < 2; ++mi) ao[mi] = (wy * 32 + mi * 16 + l15) * 32 + rswz;
#pragma unroll
    for (int ni = 0; ni < 4; ++ni) bo[ni] = (wx * 64 + ni * 16 + l15) * 32 + rswz;

    // prologue: stage tiles 0..3 into slots 0..3; wait tile 0; read its frags
#pragma unroll
    for (int p = 0; p < 4; ++p) {
        async16(aP, aDst + p * 4096);
        async16(bP, bDst + p * 4096);
        aP += 32; bP += 32;
    }
    asm volatile("s_waitcnt vmcnt(6)" ::: "memory");
    BAR();

    bf16x8 fa0[2], fb0[4], fa1[2], fb1[4];
    readf(&At[0][0], &Bt[0][0], 0, ao, bo, fa0, fb0);

    int sStage = 4;   // slot for tile t+4
    int sPf = 1;      // slot for tile t+1
    int nMain = nIter - 4;   // even

    for (int t = 0; t < nMain; t += 2) {
        // ---- even iter t: compute tile t (set0), prefetch t+1 (set1) ----
        asm volatile("s_waitcnt vmcnt(4)" ::: "memory");
        BAR();
        async16(aP, aDst + sStage * 4096);
        async16(bP, bDst + sStage * 4096);
        aP += 32; bP += 32;
        sStage = (sStage == 4) ? 0 : sStage + 1;
        mfma8(fa0, fb0, acc);
        readf(&At[0][0], &Bt[0][0], sPf, ao, bo, fa1, fb1);
        sPf = (sPf == 4) ? 0 : sPf + 1;
        // ---- odd iter t+1: compute tile t+1 (set1), prefetch t+2 (set0) ----
        asm volatile("s_waitcnt vmcnt(4)" ::: "memory");
        BAR();
        async16(aP, aDst + sStage * 4096);
        async16(bP, bDst + sStage * 4096);
        aP += 32; bP += 32;
        sStage = (sStage == 4) ? 0 : sStage + 1;
        mfma8(fa1, fb1, acc);
        readf(&At[0][0], &Bt[0][0], sPf, ao, bo, fa0, fb0);
        sPf = (sPf == 4) ? 0 : sPf + 1;
    }

    // ---- tail: 4 iters (nIter-4 .. nIter-1), current set = set0 ----
    asm volatile("s_waitcnt vmcnt(4)" ::: "memory");
    BAR();
    mfma8(fa0, fb0, acc);
    readf(&At[0][0], &Bt[0][0], sPf, ao, bo, fa1, fb1);
    sPf = (sPf == 4) ? 0 : sPf + 1;

    asm volatile("s_waitcnt vmcnt(2)" ::: "memory");
    BAR();
    mfma8(fa1, fb1, acc);
    readf(&At[0][0], &Bt[0][0], sPf, ao, bo, fa0, fb0);
    sPf = (sPf == 4) ? 0 : sPf + 1;

    asm volatile("s_waitcnt vmcnt(0)" ::: "memory");
    BAR();
    mfma8(fa0, fb0, acc);
    readf(&At[0][0], &Bt[0][0], sPf, ao, bo, fa1, fb1);

    mfma8(fa1, fb1, acc);

    // ---- epilogue ----
#pragma unroll
    for (int ni = 0; ni < 4; ++ni) {
        int col = n0 + wx * 64 + ni * 16 + l15;
        float bv = (EPI == 1 || EPI == 2) ? bias[col] : 0.f;
#pragma unroll
        for (int mi = 0; mi < 2; ++mi) {
            int row0 = m0 + wy * 32 + mi * 16 + quad * 4;
#pragma unroll
            for (int r = 0; r < 4; ++r) {
                size_t idx = (size_t)(row0 + r) * N + col;
                float val = acc[mi][ni][r];
                if constexpr (EPI == 0) {
                    ((bf16*)Cout)[(size_t)z * sC + idx] = __float2bfloat16(val);
                } else if constexpr (EPI == 1) {
                    ((float*)Cout)[idx] = val + bv + Res[idx];
                } else if constexpr (EPI == 2) {
                    val += bv;
                    val = 0.5f * val * (1.f + erff(val * 0.70710678118654752f));
                    ((bf16*)Cout)[idx] = __float2bfloat16(val);
                } else {
                    ((float*)Cout)[(size_t)z * sC + idx] = val;
                }
            }
        }
    }
}

// ---------------------------------------------------------------------------
// Workspace (peak 62 MB):
//   [0,16)  : hnorm bf16 -> attn bf16 (step4 out) -> mnorm bf16 (step6 out)
//   [16,18) : uvT bf16 (dead after step 2) -> qg fp32 (written step 2b)
//   [18,20) : kg fp32
//   [20,36) : hnormT bf16            -+ tbuf bf16 [20,52) after step 4
//   [36,52) : qkraw fp32 4x4MB split-K partials (dead after 2b) -> Mbuf bf16
//   [52,54) : proj_w bf16   [54,58): up_w bf16   [58,62): down_w bf16
//   h1 lives in d_out (fp32); step 8 does same-index RMW (alias-safe).
// ---------------------------------------------------------------------------
extern "C" void kernel_launch(void* const* d_in, const int* in_sizes, int n_in,
                              void* d_out, int out_size, void* d_ws, size_t ws_size,
                              hipStream_t stream) {
    const float* h           = (const float*)d_in[0];
    const float* k_base      = (const float*)d_in[1];
    const float* decay_logit = (const float*)d_in[2];
    const float* gate_logit  = (const float*)d_in[3];
    const float* alpha_logit = (const float*)d_in[4];
    const float* u           = (const float*)d_in[5];
    const float* v           = (const float*)d_in[6];
    const float* proj_w      = (const float*)d_in[7];
    const float* proj_b      = (const float*)d_in[8];
    const float* norm1_scale = (const float*)d_in[9];
    const float* norm2_scale = (const float*)d_in[10];
    const float* up_w        = (const float*)d_in[11];
    const float* up_b        = (const float*)d_in[12];
    const float* down_w      = (const float*)d_in[13];
    const float* down_b      = (const float*)d_in[14];

    const size_t MB = 1048576;
    char* ws = (char*)d_ws;
    bf16*  hnorm   = (bf16*)(ws);                  // 16 MB
    bf16*  uvT     = (bf16*)(ws + 16 * MB);        // 256 KB (dead after step 2)
    float* qg      = (float*)(ws + 16 * MB);       //  2 MB (written step 2b)
    float* kg      = (float*)(ws + 18 * MB);       //  2 MB
    bf16*  hnormT  = (bf16*)(ws + 20 * MB);        // 16 MB
    float* qkraw   = (float*)(ws + 36 * MB);       // 16 MB partials (pre-buildM)
    bf16*  Mbuf    = (bf16*)(ws + 36 * MB);        // 16 MB (step 3 out)
    bf16*  proj_wb = (bf16*)(ws + 52 * MB);        //  2 MB
    bf16*  up_wb   = (bf16*)(ws + 54 * MB);        //  4 MB
    bf16*  down_wb = (bf16*)(ws + 58 * MB);        //  4 MB
    bf16*  attn    = hnorm;                        // [0,16) after qk GEMM
    bf16*  mnorm   = hnorm;
    bf16*  tbuf    = hnormT;                       // [20,52) after step 4
    float* h1      = (float*)d_out;

    // 0. weight conversions (single launch) + uvT
    convert3_kernel<<<5 * D_ * D_ / 2048, 256, 0, stream>>>(
        proj_w, up_w, down_w, proj_wb, up_wb, down_wb);
    uvT_kernel<<<dim3(D_ / 64, 1, 2), 256, 0, stream>>>(u, v, uvT);

    // 1. h_norm = rmsnorm(h, norm1_scale)
    rmsnorm_kernel<<<B_ * W_, 256, 0, stream>>>(h, norm1_scale, hnorm);

    // 1b. hnormT[b][d][j] = hnorm[b][j][d]
    transpose_kernel<<<dim3(W_ / 64, D_ / 64, B_), 256, 0, stream>>>(hnorm, hnormT);

    // 2. qkraw[z] = hnorm @ [u|v] K-chunk z (deterministic split-K=4)
    mgemm_kernel<5, 4><<<dim3(B_ * W_ / 128, 1, 4), 512, 0, stream>>>(
        hnorm, uvT, nullptr, nullptr, qkraw, B_ * W_, 128, D_,
        0, 0, (long)B_ * W_ * 128, 0);

    // 2b. sum partials, l2norm halves, gamma^{+/-i} -> qg, kg (fp32)
    qk_epilogue_kernel<<<B_ * W_, 128, 0, stream>>>(qkraw, decay_logit, qg, kg);

    // 3. M = causal * (gate*k_base + alpha*scores)
    buildM_kernel<<<dim3(W_ / 32, W_ / 32, B_), dim3(16, 16), 0, stream>>>(
        qg, kg, k_base, gate_logit, alpha_logit, Mbuf);

    // 4. attn = M @ hnorm  (B = hnormT, batched via z, causal k-trunc)
    mgemm_kernel<0, 1><<<dim3(W_ / 128, D_ / 128, B_), 512, 0, stream>>>(
        Mbuf, hnormT, nullptr, nullptr, attn, W_, D_, W_,
        (long)W_ * W_, (long)W_ * D_, (long)W_ * D_, 1);

    // 5. h1 = h + attn @ proj_w^T + proj_b   -> d_out (fp32)
    mgemm_kernel<1, 1><<<dim3(B_ * W_ / 128, D_ / 128, 1), 512, 0, stream>>>(
        attn, proj_wb, h, proj_b, h1, B_ * W_, D_, D_, 0, 0, 0, 0);

    // 6. mnorm = rmsnorm(h1, norm2_scale)
    rmsnorm_kernel<<<B_ * W_, 256, 0, stream>>>(h1, norm2_scale, mnorm);

    // 7. t = gelu(mnorm @ up_w^T + up_b)     -> tbuf (bf16)
    mgemm_kernel<2, 1><<<dim3(B_ * W_ / 128, 2 * D_ / 128, 1), 512, 0, stream>>>(
        mnorm, up_wb, nullptr, up_b, tbuf, B_ * W_, 2 * D_, D_, 0, 0, 0, 0);

    // 8. out = h1 + t @ down_w^T + down_b  (h1 aliases d_out, same-idx RMW)
    mgemm_kernel<1, 1><<<dim3(B_ * W_ / 128, D_ / 128, 1), 512, 0, stream>>>(
        tbuf, down_wb, h1, down_b, (float*)d_out, B_ * W_, D_, 2 * D_, 0, 0, 0, 0);
}